// Round 6
// baseline (88.649 us; speedup 1.0000x reference)
//
#include <hip/hip_runtime.h>

// Not-a-knot cubic spline upsample (512 x 8192 f32 -> 512 x 32768 f32).
//
// Fully fused, LDS-free, barrier-free formulation.
// One thread = 16 consecutive outputs (qr = 16*gr .. +15), spanning <= 5
// intervals -> knots i0..i0+5. M[j] via register 25-tap Green conv on y:
//   M[j] = W0*y[j] + sum_{d=1..12} W1*r^(d-1) * (y[j-d]+y[j+d]),
//   r = sqrt(3)-2, W0 = 6C(2r-2), W1 = 6C(1-r)^2, C = 1/(2 sqrt(3)).
// Window y[i0-12 .. i0+19] = 8 unaligned-ok dwordx4 loads; adjacent lanes'
// windows shift by ~4 floats -> wave loads are ~1KB dense (coalesced, L1-hot).
// Interval selection per output u is COMPILE-TIME: di_u = c_u + (rr0 >= T_u),
// so all coefficient indexing is static (no scratch).
// Edge threads (8 per row) use the reflected-RHS b-space conv (R1-proven).

typedef float f32x4  __attribute__((ext_vector_type(4)));
typedef float f32x4u __attribute__((ext_vector_type(4), aligned(4)));

constexpr int W  = 8192;
constexpr int WU = 32768;

constexpr float Rr = -0.26794919243112270647f;  // sqrt(3)-2
constexpr float W0 = -4.39230484541326386f;     // 6C(2r-2)
constexpr float W1 =  2.78460969082652752f;     // 6C(1-r)^2
constexpr float Cg =  0.288675134594812882f;    // 1/(2 sqrt(3))

__device__ __forceinline__ float convg(const float* __restrict__ xr, int j,
                                       float M1g, float Mn2g) {
    // b-space Green conv with odd reflection about -1 and n, K=10.
    const int n = W - 4;
    auto bg = [&](int m) -> float {
        if (m == -1 || m == n) return 0.f;
        float sgn = 1.f;
        if (m < -1)      { m = -2 - m;   sgn = -1.f; }
        else if (m > n)  { m = 2*n - m;  sgn = -1.f; }
        int p = m + 2;                    // p in [2, W-2] -> reads y[1..W-1]
        float v = 6.f * (xr[p+1] - 2.f*xr[p] + xr[p-1]);
        if (m == 0)     v -= M1g;
        if (m == n - 1) v -= Mn2g;
        return sgn * v;
    };
    const int mc = j - 2;
    float acc = Cg * bg(mc);
    float wr  = Cg;
    #pragma unroll
    for (int d = 1; d <= 10; ++d) {
        wr  *= Rr;
        acc += wr * (bg(mc - d) + bg(mc + d));
    }
    return acc;
}

__global__ __launch_bounds__(256, 6)
void spline_kernel(const float* __restrict__ x, float* __restrict__ out)
{
    const int g  = blockIdx.x * 256 + threadIdx.x;
    const int r  = g >> 11;                    // 2048 16-output groups per row
    const int gr = g & 2047;
    const float* __restrict__ xr = x + (size_t)r * W;
    const int qr = gr << 4;

    const unsigned num = (unsigned)qr * (unsigned)(W - 1);
    const int i0  = (int)(num / (unsigned)(WU - 1));   // magic-div
    const int rr0 = (int)(num - (unsigned)i0 * (unsigned)(WU - 1));

    float Y[6], M[6];
    const bool fast = (i0 >= 12) && (i0 <= 8172);      // window fully in-row
    if (fast) {
        float w[32];
        const float* base = xr + (i0 - 12);
        #pragma unroll
        for (int k = 0; k < 8; ++k) {
            f32x4 v = *(const f32x4u*)(base + 4*k);    // 4B-aligned dwordx4
            w[4*k+0]=v.x; w[4*k+1]=v.y; w[4*k+2]=v.z; w[4*k+3]=v.w;
        }
        #pragma unroll
        for (int k = 0; k < 6; ++k) {
            float acc = W0 * w[12+k];
            float wd  = W1;
            #pragma unroll
            for (int d = 1; d <= 12; ++d) {
                acc += wd * (w[12+k-d] + w[12+k+d]);
                wd  *= Rr;                              // folds to literals
            }
            M[k] = acc;
            Y[k] = w[12+k];
        }
    } else {
        // 8 threads per row: reflected-RHS route, global scalar reads.
        const float M1g  = xr[0]   - 2.f*xr[1]   + xr[2];
        const float Mn2g = xr[W-1] - 2.f*xr[W-2] + xr[W-3];
        #pragma unroll
        for (int k = 0; k < 6; ++k) {
            int j = i0 + k; if (j > W-1) j = W-1;
            Y[k] = xr[j];
            float m;
            if (j == 0)          m = 2.f*M1g  - convg(xr, 2,   M1g, Mn2g);
            else if (j == 1)     m = M1g;
            else if (j == W-2)   m = Mn2g;
            else if (j == W-1)   m = 2.f*Mn2g - convg(xr, W-3, M1g, Mn2g);
            else                 m = convg(xr, j, M1g, Mn2g);
            M[k] = m;
        }
    }

    // Per-interval cubic coefficients (intervals i0+0 .. i0+4).
    float C0[5], C1[5], C2[5], C3[5];
    #pragma unroll
    for (int k = 0; k < 5; ++k) {
        C0[k] = Y[k];
        C1[k] = (Y[k+1] - Y[k]) - (2.f*M[k] + M[k+1]) * (1.f/6.f);
        C2[k] = 0.5f * M[k];
        C3[k] = (M[k+1] - M[k]) * (1.f/6.f);
    }

    float* __restrict__ op = out + (size_t)r * WU + qr;
    #pragma unroll
    for (int s = 0; s < 4; ++s) {
        float res[4];
        #pragma unroll
        for (int v = 0; v < 4; ++v) {
            const int u = 4*s + v;
            const int A = u * (W - 1);
            const int c = A / (WU - 1);            // compile-time constants
            const int R = A - c * (WU - 1);
            const int T = (WU - 1) - R;
            const bool f = (rr0 >= T);             // u=0: T=32767 -> never
            float t  = (float)(rr0 + R) * (1.f/32767.f) - (f ? 1.f : 0.f);
            float d0 = f ? C0[c+1] : C0[c];
            float d1 = f ? C1[c+1] : C1[c];
            float d2 = f ? C2[c+1] : C2[c];
            float d3 = f ? C3[c+1] : C3[c];
            res[v] = d0 + t * (d1 + t * (d2 + t * d3));
        }
        f32x4 o = {res[0], res[1], res[2], res[3]};
        __builtin_nontemporal_store(o, (f32x4*)(op + 4*s));
    }
}

extern "C" void kernel_launch(void* const* d_in, const int* in_sizes, int n_in,
                              void* d_out, int out_size, void* d_ws, size_t ws_size,
                              hipStream_t stream) {
    const float* x = (const float*)d_in[0];
    float* out = (float*)d_out;
    const int B = in_sizes[0] / W;                 // 512
    const int nthreads = B * (WU / 16);            // 1,048,576
    dim3 grid(nthreads / 256), block(256);
    hipLaunchKernelGGL(spline_kernel, grid, block, 0, stream, x, out);
}

// Round 7
// 68.290 us; speedup vs baseline: 1.2981x; 1.2981x over previous
//
#include <hip/hip_runtime.h>

// Not-a-knot cubic spline upsample (512 x 8192 f32 -> 512 x 32768 f32).
//
// Fully fused, LDS-free, barrier-free. ONE THREAD = ONE QUAD of 4 consecutive
// outputs -> wave stores are 64 x 16B contiguous = 1KB dense per instruction
// (R4's proven-clean write pattern; R6's 64B/thread mapping caused 2.7x HBM
// write amplification via strided 16B NT stores).
//
// M[j] via register Green conv on y (K=8):
//   M[j] = W0*y[j] + sum_{d=1..8} W1*r^(d-1) * (y[j-d]+y[j+d]),
//   r = sqrt(3)-2;  truncation ~7e-4 << 0.03 error floor.
// Quad spans <= 2 intervals -> knots i0..i0+2, window y[i0-8..i0+11]
// = 5 dword-aligned dwordx4 loads; lanes shift 4B/lane -> dense, L1-hot.
// Edge quads (i0<8 or i0>8180, ~20/row) use reflected-RHS route (R1-proven);
// at i0=8 the boundary-image correction is ~|r|^14 ~ 1e-8 -> interior conv ok.

typedef float f32x4  __attribute__((ext_vector_type(4)));
typedef float f32x4u __attribute__((ext_vector_type(4), aligned(4)));

constexpr int W  = 8192;
constexpr int WU = 32768;

constexpr float Rr  = -0.26794919243112270647f;  // sqrt(3)-2
constexpr float W0c = -4.39230484541326386f;     // 6C(2r-2)
constexpr float W1c =  2.78460969082652752f;     // 6C(1-r)^2
constexpr float Cg  =  0.288675134594812882f;    // C = 1/(2 sqrt(3))

__device__ __forceinline__ float convg(const float* __restrict__ xr, int j,
                                       float M1g, float Mn2g) {
    // b-space Green conv with odd reflection about -1 and n, K=10 (R1-proven).
    const int n = W - 4;
    auto bg = [&](int m) -> float {
        if (m == -1 || m == n) return 0.f;
        float sgn = 1.f;
        if (m < -1)      { m = -2 - m;   sgn = -1.f; }
        else if (m > n)  { m = 2*n - m;  sgn = -1.f; }
        int p = m + 2;                    // p in [2, W-2] -> reads y[1..W-1]
        float v = 6.f * (xr[p+1] - 2.f*xr[p] + xr[p-1]);
        if (m == 0)     v -= M1g;
        if (m == n - 1) v -= Mn2g;
        return sgn * v;
    };
    const int mc = j - 2;
    float acc = Cg * bg(mc);
    float wr  = Cg;
    #pragma unroll
    for (int d = 1; d <= 10; ++d) {
        wr  *= Rr;
        acc += wr * (bg(mc - d) + bg(mc + d));
    }
    return acc;
}

__global__ __launch_bounds__(256)
void spline_kernel(const float* __restrict__ x, float* __restrict__ out)
{
    const int g  = blockIdx.x * 256 + threadIdx.x;   // one quad per thread
    const int r  = g >> 13;                          // 8192 quads per row
    const int qr = (g & 8191) << 2;                  // first output in row
    const float* __restrict__ xr = x + (size_t)r * W;

    const unsigned num = (unsigned)qr * 8191u;
    const unsigned i0u = num / 32767u;               // magic-div
    const int i0  = (int)i0u;
    const int rr0 = (int)(num - i0u * 32767u);

    float Y0, Y1, Y2, M0, M1, M2;
    if (i0 >= 8 && i0 <= 8180) {
        // ---- fast: 20-float register window, K=8 y-space conv ----
        float w[20];
        const float* base = xr + (i0 - 8);
        #pragma unroll
        for (int k = 0; k < 5; ++k) {
            f32x4 v = *(const f32x4u*)(base + 4*k);  // 4B-aligned dwordx4
            w[4*k+0]=v.x; w[4*k+1]=v.y; w[4*k+2]=v.z; w[4*k+3]=v.w;
        }
        float a0 = W0c * w[8], a1 = W0c * w[9], a2 = W0c * w[10];
        float wd = W1c;
        #pragma unroll
        for (int d = 1; d <= 8; ++d) {
            a0 += wd * (w[8  - d] + w[8  + d]);
            a1 += wd * (w[9  - d] + w[9  + d]);
            a2 += wd * (w[10 - d] + w[10 + d]);
            wd *= Rr;                                // folds to literals
        }
        Y0 = w[8]; Y1 = w[9]; Y2 = w[10];
        M0 = a0;   M1 = a1;   M2 = a2;
    } else {
        // ---- edge quads: reflected-RHS route, global scalar reads ----
        const float M1g  = xr[0]   - 2.f*xr[1]   + xr[2];
        const float Mn2g = xr[W-1] - 2.f*xr[W-2] + xr[W-3];
        float Yk[3], Mk[3];
        #pragma unroll
        for (int k = 0; k < 3; ++k) {
            int j = i0 + k; if (j > W-1) j = W-1;    // last quad: t=0 exact
            Yk[k] = xr[j];
            float m;
            if (j == 0)        m = 2.f*M1g  - convg(xr, 2,   M1g, Mn2g);
            else if (j == 1)   m = M1g;
            else if (j == W-2) m = Mn2g;
            else if (j == W-1) m = 2.f*Mn2g - convg(xr, W-3, M1g, Mn2g);
            else               m = convg(xr, j, M1g, Mn2g);
            Mk[k] = m;
        }
        Y0 = Yk[0]; Y1 = Yk[1]; Y2 = Yk[2];
        M0 = Mk[0]; M1 = Mk[1]; M2 = Mk[2];
    }

    // Cubic coefficients for intervals a=(i0) and b=(i0+1).
    const float A0 = Y0, A1 = (Y1-Y0) - (2.f*M0 + M1)*(1.f/6.f),
                A2 = 0.5f*M0, A3 = (M1 - M0)*(1.f/6.f);
    const float B0 = Y1, B1 = (Y2-Y1) - (2.f*M1 + M2)*(1.f/6.f),
                B2 = 0.5f*M1, B3 = (M2 - M1)*(1.f/6.f);

    float res[4];
    #pragma unroll
    for (int u = 0; u < 4; ++u) {
        const int Au = u * (W - 1);                  // compile-time
        const int T  = (WU - 1) - Au;
        const bool f = (rr0 >= T);                   // u=0: never
        float t  = (float)(rr0 + Au) * (1.f/32767.f) - (f ? 1.f : 0.f);
        float d0 = f ? B0 : A0;
        float d1 = f ? B1 : A1;
        float d2 = f ? B2 : A2;
        float d3 = f ? B3 : A3;
        res[u] = d0 + t * (d1 + t * (d2 + t * d3));
    }
    f32x4 o = {res[0], res[1], res[2], res[3]};
    *(f32x4*)(out + (size_t)r * WU + qr) = o;        // 1KB dense per wave
}

extern "C" void kernel_launch(void* const* d_in, const int* in_sizes, int n_in,
                              void* d_out, int out_size, void* d_ws, size_t ws_size,
                              hipStream_t stream) {
    const float* x = (const float*)d_in[0];
    float* out = (float*)d_out;
    const int B = in_sizes[0] / W;                   // 512
    const int nthreads = B * (WU / 4);               // 4,194,304
    dim3 grid(nthreads / 256), block(256);
    hipLaunchKernelGGL(spline_kernel, grid, block, 0, stream, x, out);
}

// Round 8
// 32.022 us; speedup vs baseline: 2.7684x; 2.1326x over previous
//
#include <hip/hip_runtime.h>

// Not-a-knot cubic spline upsample (512 x 8192 f32 -> 512 x 32768 f32).
//
// Persistent-block 2-phase pipeline (T3/T14): one block per row, 16 tiles of
// 512 knots. Tile k+1 is loaded global->REG early (dense 16B-aligned dwordx4,
// lane-stride 16B = the proven-fast pattern; R6/R7 showed per-lane sliding
// windows are ~3x slower) and written to LDS late (after the mid barrier), so
// HBM latency hides under conv+eval of tile k. Conv / boundary / eval phases
// are VERBATIM R4 (proven, absmax 0.03125).
//
// M[j] = W0*y[j] + sum_{d=1..12} W1*r^(d-1)*(y[j-d]+y[j+d]), r = sqrt(3)-2.
// Boundary tiles (0, 15): reflected-RHS b-space conv (R1-proven), K=10.

typedef float f32x4 __attribute__((ext_vector_type(4)));
typedef float f32x2 __attribute__((ext_vector_type(2)));

constexpr int W    = 8192;
constexpr int WU   = 32768;
constexpr int TILE = 512;
constexpr int NT   = W / TILE;        // 16 tiles per row
constexpr int HL   = 16;
constexpr int YSN  = 544;             // ys[idx] = x[s0-16+idx]
constexpr int MSN  = 516;             // ym[idx] = (y,M) at knot j = s0-1+idx
constexpr int KB   = 10;
constexpr int BTN  = 538;

__global__ __launch_bounds__(256)
void spline_kernel(const float* __restrict__ x, float* __restrict__ out)
{
    const int row = blockIdx.x;
    const int tid = threadIdx.x;
    const int n   = W - 4;
    const float* __restrict__ xr   = x   + (size_t)row * W;
    float*       __restrict__ orow = out + (size_t)row * WU;

    __shared__ __align__(16) float ys[2][YSN];
    __shared__ __align__(16) f32x2 ym[MSN];
    __shared__ float bt[BTN];

    // Dense staged load for one tile: thread t<136 owns ys[4t..4t+3].
    // base = tile*512-16+4t is a multiple of 4 elements -> 16B aligned.
    auto LOAD = [&](int tile) -> f32x4 {
        f32x4 v = {0.f, 0.f, 0.f, 0.f};
        if (tid < 136) {
            int base = tile * TILE - HL + 4 * tid;
            if (tile == 0 || tile == NT - 1) {        // edge tiles: clamp
                #pragma unroll
                for (int e = 0; e < 4; ++e) {
                    int g = base + e;
                    g = g < 0 ? 0 : (g > W - 1 ? W - 1 : g);
                    v[e] = xr[g];
                }
            } else {
                v = *(const f32x4*)(xr + base);
            }
        }
        return v;
    };

    // Prologue: stage tile 0, prefetch tile 1.
    f32x4 regA = LOAD(0);
    if (tid < 136) *(f32x4*)&ys[0][4 * tid] = regA;
    __syncthreads();
    regA = LOAD(1);
    int cur = 0;

    for (int k = 0; k < NT; ++k) {
        f32x4 regB = {0.f, 0.f, 0.f, 0.f};
        if (k + 2 < NT) regB = LOAD(k + 2);           // issue early (hidden)

        const int s0  = k * TILE;
        const int YS0 = s0 - HL;
        float* ysc = ys[cur];
        const bool boundary = (k == 0) || (k == NT - 1);

        if (!boundary) {
            // ---- interior conv: 4 knots/thread, 8x ds_read_b128 (R4) ----
            if (tid < 129) {
                const f32x4* ys4 = (const f32x4*)ysc;
                float w[32];
                #pragma unroll
                for (int kk = 0; kk < 8; ++kk) {      // w[m] = ysc[4*tid+m]
                    f32x4 v = ys4[tid + kk];
                    w[4*kk+0]=v.x; w[4*kk+1]=v.y; w[4*kk+2]=v.z; w[4*kk+3]=v.w;
                }
                float acc[4];
                #pragma unroll
                for (int c = 0; c < 4; ++c)
                    acc[c] = -4.39230484541326386f * w[15 + c];
                float wd = 2.78460969082652752f;      // sqrt(3)*(1-r)^2
                #pragma unroll
                for (int d = 1; d <= 12; ++d) {
                    #pragma unroll
                    for (int c = 0; c < 4; ++c)
                        acc[c] += wd * (w[15 + c - d] + w[15 + c + d]);
                    wd *= -0.26794919243112270647f;   // folds to literals
                }
                f32x4 o0 = {w[15], acc[0], w[16], acc[1]};
                f32x4 o1 = {w[17], acc[2], w[18], acc[3]};
                *(f32x4*)&ym[4 * tid]     = o0;
                *(f32x4*)&ym[4 * tid + 2] = o1;
            }
        } else {
            // ---- boundary: reflected-RHS Green's conv (R1-proven) ----
            auto Dp = [&](int p) -> float {
                int a = p - YS0;
                return 6.0f * (ysc[a + 1] - 2.0f * ysc[a] + ysc[a - 1]);
            };
            auto M1v = [&]() -> float {
                int a = -YS0; return ysc[a] - 2.0f * ysc[a + 1] + ysc[a + 2];
            };
            auto Mn2v = [&]() -> float {
                int a = (W - 1) - YS0;
                return ysc[a] - 2.0f * ysc[a - 1] + ysc[a - 2];
            };
            auto bval = [&](int m) -> float {
                if (m == -1 || m == n) return 0.f;
                float sgn = 1.f;
                if (m < -1)     { m = -2 - m;    sgn = -1.f; }
                else if (m > n) { m = 2 * n - m; sgn = -1.f; }
                float v = Dp(m + 2);
                if (m == 0)     v -= M1v();
                if (m == n - 1) v -= Mn2v();
                return sgn * v;
            };
            const int BT0 = s0 - 3 - KB;
            for (int idx = tid; idx < BTN; idx += 256)
                bt[idx] = bval(BT0 + idx);
            __syncthreads();
            auto convb = [&](int j) -> float {
                int base = j - 2 - BT0;
                float acc = 0.288675134594812882f * bt[base];
                float wr  = 0.288675134594812882f;
                #pragma unroll
                for (int d = 1; d <= KB; ++d) {
                    wr  *= -0.26794919243112270647f;
                    acc += wr * (bt[base - d] + bt[base + d]);
                }
                return acc;
            };
            for (int idx = tid; idx < MSN; idx += 256) {
                int j = s0 - 1 + idx;
                j = j < 0 ? 0 : (j > W - 1 ? W - 1 : j);
                float m;
                if (j == 0)          m = 2.f*M1v()  - convb(2);
                else if (j == 1)     m = M1v();
                else if (j == W - 2) m = Mn2v();
                else if (j == W - 1) m = 2.f*Mn2v() - convb(W - 3);
                else                 m = convb(j);
                ym[idx] = (f32x2){ysc[idx + 15], m};
            }
        }
        __syncthreads();                              // ym ready

        // ---- eval: 8 outputs/thread, 2 dense f32x4 stores (R4) ----
        const int qbase = s0 * (WU / W);
        #pragma unroll
        for (int it = 0; it < 2; ++it) {
            int q0  = qbase + (tid + it * 256) * 4;
            int num = q0 * (W - 1);
            int i0  = num / (WU - 1);                 // magic-div
            int rr  = num - i0 * (WU - 1);
            int kM  = i0 - s0 + 1;
            f32x2 p0 = ym[kM], p1 = ym[kM + 1], p2 = ym[kM + 2];
            float res[4];
            int di = 0;
            #pragma unroll
            for (int u = 0; u < 4; ++u) {
                float t  = (float)rr * (1.0f / (float)(WU - 1));
                float y0 = di ? p1.x : p0.x;
                float y1 = di ? p2.x : p1.x;
                float m0 = di ? p1.y : p0.y;
                float m1 = di ? p2.y : p1.y;
                float bb = (y1 - y0) - (2.f*m0 + m1) * (1.f/6.f);
                res[u] = y0 + t * (bb + t * (0.5f*m0 + t * (m1 - m0) * (1.f/6.f)));
                rr += (W - 1);
                if (rr >= WU - 1) { rr -= (WU - 1); di = 1; }
            }
            f32x4 o = {res[0], res[1], res[2], res[3]};
            *(f32x4*)(orow + q0) = o;                 // 1KB dense per wave
        }

        // ---- write next tile's staged regs to the other LDS buffer ----
        if (k + 1 < NT) {
            if (tid < 136) *(f32x4*)&ys[cur ^ 1][4 * tid] = regA;
        }
        __syncthreads();
        regA = regB;
        cur ^= 1;
    }
}

extern "C" void kernel_launch(void* const* d_in, const int* in_sizes, int n_in,
                              void* d_out, int out_size, void* d_ws, size_t ws_size,
                              hipStream_t stream) {
    const float* x = (const float*)d_in[0];
    float* out = (float*)d_out;
    const int B = in_sizes[0] / W;                    // 512 rows
    dim3 grid(B), block(256);
    hipLaunchKernelGGL(spline_kernel, grid, block, 0, stream, x, out);
}

// Round 9
// 24.925 us; speedup vs baseline: 3.5566x; 1.2847x over previous
//
#include <hip/hip_runtime.h>

// Not-a-knot cubic spline upsample (512 x 8192 f32 -> 512 x 32768 f32).
//
// 2048 blocks (8/CU) x 4 pipelined tiles each: tile k+1 global->reg load
// issues before conv/eval of tile k (T14), so HBM latency hides under
// compute while occupancy stays at R4's proven level (R8's 512-block
// version starved the CU at 2 blocks/CU).
// Conv K=8 (R7-proven accuracy), emits per-interval cubic coefficients:
//   Ca[i] = (C0, C1), Cb[i] = (C2, C3);  out = C0 + t(C1 + t(C2 + t C3))
// so eval = 2x ds_read_b64 + fma-chain per output (no cndmask shuffle).
// M[j] weights: W0 = 12C(r-1), W_s = 6C(1-r)^2 r^(s-1), r = sqrt(3)-2.
// Boundary tiles (0, 15): reflected-RHS b-space conv (R1-proven), K=10.

typedef float f32x4 __attribute__((ext_vector_type(4)));
typedef float f32x2 __attribute__((ext_vector_type(2)));

constexpr int W    = 8192;
constexpr int WU   = 32768;
constexpr int TILE = 512;
constexpr int TPB  = 4;              // tiles per block
constexpr int HL   = 16;
constexpr int YSN  = 544;            // ys[idx] = y[s0-16+idx]
constexpr int CN   = 516;            // coeff entries, interval i = s0-1+idx
constexpr int KB   = 10;
constexpr int BTN  = 538;
constexpr int MTN  = 520;            // boundary M scratch (517 used)

constexpr float Rr  = -0.26794919243112270647f;  // sqrt(3)-2
constexpr float W0c = -4.39230484541326386f;     // 12C(r-1)
constexpr float W1c =  2.78460969082652752f;     // 6C(1-r)^2
constexpr float Cg  =  0.288675134594812882f;    // C = 1/(2 sqrt(3))

__global__ __launch_bounds__(256)
void spline_kernel(const float* __restrict__ x, float* __restrict__ out)
{
    const int row = blockIdx.y;
    const int t0  = blockIdx.x * TPB;            // first tile of this block
    const int tid = threadIdx.x;
    const int n   = W - 4;

    const float* __restrict__ xr   = x   + (size_t)row * W;
    float*       __restrict__ orow = out + (size_t)row * WU;

    __shared__ __align__(16) float ys[2][YSN];
    __shared__ __align__(16) f32x2 Ca[CN];       // (C0, C1)
    __shared__ __align__(16) f32x2 Cb[CN];       // (C2, C3)
    __shared__ float bt[BTN];
    __shared__ float Mtmp[MTN];

    // Dense staged load: thread t<136 owns ys[4t..4t+3] (16B-aligned).
    auto LOAD = [&](int tile) -> f32x4 {
        f32x4 v = {0.f, 0.f, 0.f, 0.f};
        if (tid < 136) {
            int base = tile * TILE - HL + 4 * tid;
            if (tile == 0 || tile == 15) {       // edge tiles: clamp
                #pragma unroll
                for (int e = 0; e < 4; ++e) {
                    int g = base + e;
                    g = g < 0 ? 0 : (g > W - 1 ? W - 1 : g);
                    v[e] = xr[g];
                }
            } else {
                v = *(const f32x4*)(xr + base);
            }
        }
        return v;
    };

    f32x4 regA = LOAD(t0);
    if (tid < 136) *(f32x4*)&ys[0][4 * tid] = regA;
    __syncthreads();
    regA = LOAD(t0 + 1);

    int cur = 0;
    for (int k = 0; k < TPB; ++k) {
        const int tile = t0 + k;
        const int s0   = tile * TILE;

        f32x4 regB = {0.f, 0.f, 0.f, 0.f};
        if (k + 2 < TPB) regB = LOAD(t0 + k + 2);     // issue early (hidden)

        float* ysc = ys[cur];
        const bool boundary = (tile == 0) || (tile == 15);

        if (!boundary) {
            // ---- interior: 5 M's + 4 coeff-sets per thread, K=8 ----
            if (tid < 129) {
                const f32x4* ys4 = (const f32x4*)ysc;
                float w[24];                     // w[m] = ysc[4*tid + 4 + m]
                #pragma unroll
                for (int kk = 0; kk < 6; ++kk) {
                    f32x4 v = ys4[tid + 1 + kk];
                    w[4*kk+0]=v.x; w[4*kk+1]=v.y; w[4*kk+2]=v.z; w[4*kk+3]=v.w;
                }
                float a[5];                      // M at i = s0-1+4*tid+d
                #pragma unroll
                for (int d = 0; d < 5; ++d) a[d] = W0c * w[11 + d];
                float wd = W1c;
                #pragma unroll
                for (int dd = 1; dd <= 8; ++dd) {
                    #pragma unroll
                    for (int d = 0; d < 5; ++d)
                        a[d] += wd * (w[11 + d - dd] + w[11 + d + dd]);
                    wd *= Rr;                    // folds to literals
                }
                #pragma unroll
                for (int c = 0; c < 4; ++c) {    // intervals idx = 4*tid+c
                    float y0 = w[11 + c], y1 = w[12 + c];
                    float c1 = (y1 - y0) - (2.f*a[c] + a[c+1]) * (1.f/6.f);
                    Ca[4*tid + c] = (f32x2){y0, c1};
                    Cb[4*tid + c] = (f32x2){0.5f*a[c], (a[c+1]-a[c]) * (1.f/6.f)};
                }
            }
        } else {
            // ---- boundary: reflected-RHS M (R1-proven), then coeffs ----
            const int YS0 = s0 - HL;
            auto Dp = [&](int p) -> float {
                int a2 = p - YS0;
                return 6.0f * (ysc[a2+1] - 2.0f*ysc[a2] + ysc[a2-1]);
            };
            auto M1v = [&]() -> float {
                int a2 = -YS0; return ysc[a2] - 2.f*ysc[a2+1] + ysc[a2+2];
            };
            auto Mn2v = [&]() -> float {
                int a2 = (W-1) - YS0; return ysc[a2] - 2.f*ysc[a2-1] + ysc[a2-2];
            };
            auto bval = [&](int m) -> float {
                if (m == -1 || m == n) return 0.f;
                float sgn = 1.f;
                if (m < -1)     { m = -2 - m;    sgn = -1.f; }
                else if (m > n) { m = 2*n - m;   sgn = -1.f; }
                float v = Dp(m + 2);
                if (m == 0)     v -= M1v();
                if (m == n - 1) v -= Mn2v();
                return sgn * v;
            };
            const int BT0 = s0 - 3 - KB;
            for (int idx = tid; idx < BTN; idx += 256)
                bt[idx] = bval(BT0 + idx);
            __syncthreads();
            auto convb = [&](int j) -> float {
                int base = j - 2 - BT0;
                float acc = Cg * bt[base];
                float wr  = Cg;
                #pragma unroll
                for (int d = 1; d <= KB; ++d) {
                    wr  *= Rr;
                    acc += wr * (bt[base-d] + bt[base+d]);
                }
                return acc;
            };
            for (int idx = tid; idx < 517; idx += 256) {
                int j = s0 - 1 + idx;
                j = j < 0 ? 0 : (j > W-1 ? W-1 : j);
                float m;
                if (j == 0)        m = 2.f*M1v()  - convb(2);
                else if (j == 1)   m = M1v();
                else if (j == W-2) m = Mn2v();
                else if (j == W-1) m = 2.f*Mn2v() - convb(W-3);
                else               m = convb(j);
                Mtmp[idx] = m;
            }
            __syncthreads();
            for (int idx = tid; idx < CN; idx += 256) {
                float y0 = ysc[idx + 15], y1 = ysc[idx + 16];
                float m0 = Mtmp[idx], m1 = Mtmp[idx + 1];
                Ca[idx] = (f32x2){y0, (y1 - y0) - (2.f*m0 + m1) * (1.f/6.f)};
                Cb[idx] = (f32x2){0.5f*m0, (m1 - m0) * (1.f/6.f)};
            }
        }
        __syncthreads();                          // coeffs ready

        // ---- eval: 8 outputs/thread, dynamic b64 coeff reads ----
        const int qbase = s0 * (WU / W);
        #pragma unroll
        for (int it = 0; it < 2; ++it) {
            int q0 = qbase + (tid + it * 256) * 4;
            unsigned num = (unsigned)q0 * 8191u;
            unsigned i0u = num / 32767u;          // magic-div
            int idx0 = (int)i0u - s0 + 1;
            float rr0f = (float)(num - i0u * 32767u);   // exact (< 2^24)
            float res[4];
            #pragma unroll
            for (int u = 0; u < 4; ++u) {
                const unsigned Au = 8191u * (unsigned)u;
                const float    cu = (float)Au * (1.f/32767.f);
                bool cross = (u > 0) && (rr0f >= (float)(32767u - Au));
                int  iu = idx0 + (cross ? 1 : 0);
                float t = rr0f * (1.f/32767.f) + cu - (cross ? 1.f : 0.f);
                f32x2 ca = Ca[iu], cb = Cb[iu];
                res[u] = ca.x + t * (ca.y + t * (cb.x + t * cb.y));
            }
            *(f32x4*)(orow + q0) = (f32x4){res[0], res[1], res[2], res[3]};
        }

        // ---- write prefetched tile to the other ys buffer ----
        if (k + 1 < TPB) {
            if (tid < 136) *(f32x4*)&ys[cur ^ 1][4 * tid] = regA;
        }
        __syncthreads();
        regA = regB;
        cur ^= 1;
    }
}

extern "C" void kernel_launch(void* const* d_in, const int* in_sizes, int n_in,
                              void* d_out, int out_size, void* d_ws, size_t ws_size,
                              hipStream_t stream) {
    const float* x = (const float*)d_in[0];
    float* out = (float*)d_out;
    const int B = in_sizes[0] / W;               // 512 rows
    dim3 grid(W / TILE / TPB, B), block(256);    // 4 x 512 = 2048 blocks
    hipLaunchKernelGGL(spline_kernel, grid, block, 0, stream, x, out);
}